// Round 6
// baseline (94.550 us; speedup 1.0000x reference)
//
#include <hip/hip_runtime.h>

#define BB 4
#define TT 2048
#define DD 1024
#define EE 8
#define CAP 512
#define NTOK (BB*TT)
#define OUT_HALF ((size_t)NTOK * EE * CAP)   // 33,554,432 floats per tensor

typedef float f32x4 __attribute__((ext_vector_type(4)));

// ---------------- Kernel 1: gating ----------------
// grid = 2048 blocks x 256 threads. One wave (64 lanes) per token.
__global__ __launch_bounds__(256) void gate_kernel(
    const float* __restrict__ x, const float* __restrict__ w,
    const float* __restrict__ probs,
    int* __restrict__ e0, int* __restrict__ e1enc,
    float* __restrict__ v0, float* __restrict__ v1)
{
    const int wave = threadIdx.x >> 6;
    const int lane = threadIdx.x & 63;
    const int token = blockIdx.x * 4 + wave;   // token = b*TT + t
    const float4* xt4 = (const float4*)(x + (size_t)token * DD);
    const float4* w4  = (const float4*)w;

    float acc[EE];
    #pragma unroll
    for (int e = 0; e < EE; ++e) acc[e] = 0.f;

    #pragma unroll
    for (int i = 0; i < 4; ++i) {
        float4 xv = xt4[i * 64 + lane];
        #pragma unroll
        for (int e = 0; e < EE; ++e) {
            float4 wv = w4[e * 256 + i * 64 + lane];
            acc[e] = fmaf(xv.x, wv.x, acc[e]);
            acc[e] = fmaf(xv.y, wv.y, acc[e]);
            acc[e] = fmaf(xv.z, wv.z, acc[e]);
            acc[e] = fmaf(xv.w, wv.w, acc[e]);
        }
    }
    #pragma unroll
    for (int e = 0; e < EE; ++e) {
        #pragma unroll
        for (int off = 32; off > 0; off >>= 1)
            acc[e] += __shfl_xor(acc[e], off, 64);
    }

    if (lane == 0) {
        float mx = acc[0];
        #pragma unroll
        for (int e = 1; e < EE; ++e) mx = fmaxf(mx, acc[e]);
        float ex[EE]; float Z = 0.f;
        #pragma unroll
        for (int e = 0; e < EE; ++e) { ex[e] = expf(acc[e] - mx); Z += ex[e]; }
        int i0 = 0;
        #pragma unroll
        for (int e = 1; e < EE; ++e) if (ex[e] > ex[i0]) i0 = e;
        int i1 = (i0 == 0) ? 1 : 0;
        #pragma unroll
        for (int e = 0; e < EE; ++e) if (e != i0 && ex[e] > ex[i1]) i1 = e;
        float t0 = ex[i0] / Z, t1 = ex[i1] / Z;
        float den = fmaxf(t0 + t1, 1e-9f);
        float g0 = t0 / den, g1 = t1 / den;
        float p1 = probs[NTOK + token];
        int route = (p1 < g1 / 0.2f) ? 1 : 0;
        e0[token] = i0;
        e1enc[token] = i1 | (route << 3);
        v0[token] = g0; v1[token] = g1;
    }
}

// ---------------- Kernel 2: pure zero-fill (fillBufferAligned clone) ---------
// grid = 4096 blocks x 256 threads; each thread stores 16 float4 grid-strided.
// Single stream, no branches, no loads — should match the runtime fill's
// ~7 TB/s. 4096*256*16 = 16,777,216 float4 = the full 268 MB output.
__global__ __launch_bounds__(256) void zero_kernel(f32x4* __restrict__ out)
{
    const size_t stride = (size_t)4096 * 256;
    size_t idx = (size_t)blockIdx.x * 256 + threadIdx.x;
    f32x4 z = (f32x4)(0.f);
    #pragma unroll
    for (int k = 0; k < 16; ++k)
        out[idx + (size_t)k * stride] = z;
}

// ---------------- Kernel 3: fused capacity scan + sparse scatter -------------
// grid = 32 blocks x 64 threads, one wave per (batch, expert). No LDS/syncs.
// Computes positions via ballot ranking and directly rewrites the <=2 nonzero
// dwords per (token, rank) into the just-zeroed tensors.
__global__ __launch_bounds__(64) void scan_scatter_kernel(
    const int* __restrict__ e0, const int* __restrict__ e1enc,
    const float* __restrict__ v0, const float* __restrict__ v1,
    float* __restrict__ dispatch, float* __restrict__ combine)
{
    const int b = blockIdx.x >> 3;
    const int e = blockIdx.x & 7;
    const int lane = threadIdx.x;
    const unsigned long long lt = (lane == 63) ? 0x7fffffffffffffffull
                                               : ((1ull << lane) - 1ull);
    const int base_tok = b * TT;

    // ---- rank 0 ----
    int ev[32];
    #pragma unroll
    for (int c = 0; c < 32; ++c) ev[c] = e0[base_tok + c * 64 + lane];

    int cnt = 0;
    #pragma unroll
    for (int c = 0; c < 32; ++c) {
        bool hit = (ev[c] == e);
        unsigned long long m = __ballot(hit);
        if (hit) {
            int pos = cnt + __popcll(m & lt);
            if (pos < CAP) {
                int tok = base_tok + c * 64 + lane;
                size_t oi = ((size_t)tok * EE + e) * CAP + pos;
                dispatch[oi] = 1.0f;
                combine[oi]  = v0[tok];
            }
        }
        cnt += __popcll(m);
    }

    // ---- rank 1 (prev = min(cnt, CAP)) ----
    int e1v[32];
    #pragma unroll
    for (int c = 0; c < 32; ++c) e1v[c] = e1enc[base_tok + c * 64 + lane];

    int cnt1 = min(cnt, CAP);
    #pragma unroll
    for (int c = 0; c < 32; ++c) {
        bool hit = ((e1v[c] & 7) == e) && (e1v[c] & 8);
        unsigned long long m = __ballot(hit);
        if (hit) {
            int pos = cnt1 + __popcll(m & lt);
            if (pos < CAP) {
                int tok = base_tok + c * 64 + lane;
                size_t oi = ((size_t)tok * EE + e) * CAP + pos;
                dispatch[oi] = 1.0f;
                combine[oi]  = v1[tok];
            }
        }
        cnt1 += __popcll(m);
    }
}

extern "C" void kernel_launch(void* const* d_in, const int* in_sizes, int n_in,
                              void* d_out, int out_size, void* d_ws, size_t ws_size,
                              hipStream_t stream) {
    const float* x     = (const float*)d_in[0];
    const float* w     = (const float*)d_in[1];
    const float* probs = (const float*)d_in[2];
    float* out = (float*)d_out;

    int*   e0 = (int*)d_ws;
    int*   e1 = e0 + NTOK;
    float* v0 = (float*)(e1 + NTOK);
    float* v1 = v0 + NTOK;

    gate_kernel<<<2048, 256, 0, stream>>>(x, w, probs, e0, e1, v0, v1);
    zero_kernel<<<4096, 256, 0, stream>>>((f32x4*)out);
    scan_scatter_kernel<<<32, 64, 0, stream>>>(e0, e1, v0, v1,
                                               out, out + OUT_HALF);
}

// Round 7
// 67.527 us; speedup vs baseline: 1.4002x; 1.4002x over previous
//
#include <hip/hip_runtime.h>

#define BB 4
#define TT 2048
#define DD 1024
#define EE 8
#define CAP 512
#define NTOK (BB*TT)
#define OUT_HALF ((size_t)NTOK * EE * CAP)   // 33,554,432 floats per tensor

typedef float f32x4 __attribute__((ext_vector_type(4)));

// ---------------- Kernel 1: gating ----------------
// grid = 2048 blocks x 256 threads. One wave (64 lanes) per token.
__global__ __launch_bounds__(256) void gate_kernel(
    const float* __restrict__ x, const float* __restrict__ w,
    const float* __restrict__ probs,
    int* __restrict__ e0, int* __restrict__ e1enc,
    float* __restrict__ v0, float* __restrict__ v1)
{
    const int wave = threadIdx.x >> 6;
    const int lane = threadIdx.x & 63;
    const int token = blockIdx.x * 4 + wave;   // token = b*TT + t
    const float4* xt4 = (const float4*)(x + (size_t)token * DD);
    const float4* w4  = (const float4*)w;

    float acc[EE];
    #pragma unroll
    for (int e = 0; e < EE; ++e) acc[e] = 0.f;

    #pragma unroll
    for (int i = 0; i < 4; ++i) {
        float4 xv = xt4[i * 64 + lane];
        #pragma unroll
        for (int e = 0; e < EE; ++e) {
            float4 wv = w4[e * 256 + i * 64 + lane];
            acc[e] = fmaf(xv.x, wv.x, acc[e]);
            acc[e] = fmaf(xv.y, wv.y, acc[e]);
            acc[e] = fmaf(xv.z, wv.z, acc[e]);
            acc[e] = fmaf(xv.w, wv.w, acc[e]);
        }
    }
    #pragma unroll
    for (int e = 0; e < EE; ++e) {
        #pragma unroll
        for (int off = 32; off > 0; off >>= 1)
            acc[e] += __shfl_xor(acc[e], off, 64);
    }

    if (lane == 0) {
        float mx = acc[0];
        #pragma unroll
        for (int e = 1; e < EE; ++e) mx = fmaxf(mx, acc[e]);
        float ex[EE]; float Z = 0.f;
        #pragma unroll
        for (int e = 0; e < EE; ++e) { ex[e] = expf(acc[e] - mx); Z += ex[e]; }
        int i0 = 0;
        #pragma unroll
        for (int e = 1; e < EE; ++e) if (ex[e] > ex[i0]) i0 = e;
        int i1 = (i0 == 0) ? 1 : 0;
        #pragma unroll
        for (int e = 0; e < EE; ++e) if (e != i0 && ex[e] > ex[i1]) i1 = e;
        float t0 = ex[i0] / Z, t1 = ex[i1] / Z;
        float den = fmaxf(t0 + t1, 1e-9f);
        float g0 = t0 / den, g1 = t1 / den;
        float p1 = probs[NTOK + token];
        int route = (p1 < g1 / 0.2f) ? 1 : 0;
        e0[token] = i0;
        e1enc[token] = i1 | (route << 3);
        v0[token] = g0; v1[token] = g1;
    }
}

// ---------------- Kernel 2: capacity scan, one wave per (batch, expert) ------
// grid = 32 blocks x 64 threads. No LDS, no __syncthreads. Writes flat
// in-row targets t0/t1 = e*CAP+pos (or -1 if dropped/unrouted).
__global__ __launch_bounds__(64) void scan_kernel(
    const int* __restrict__ e0, const int* __restrict__ e1enc,
    int* __restrict__ t0, int* __restrict__ t1)
{
    const int b = blockIdx.x >> 3;
    const int e = blockIdx.x & 7;
    const int lane = threadIdx.x;
    const unsigned long long lt = (lane == 63) ? 0x7fffffffffffffffull
                                               : ((1ull << lane) - 1ull);
    const int base_tok = b * TT;

    // ---- rank 0 ----
    int ev[32];
    #pragma unroll
    for (int c = 0; c < 32; ++c) ev[c] = e0[base_tok + c * 64 + lane];

    int cnt = 0;
    #pragma unroll
    for (int c = 0; c < 32; ++c) {
        bool hit = (ev[c] == e);
        unsigned long long m = __ballot(hit);
        if (hit) {
            int pos = cnt + __popcll(m & lt);
            t0[base_tok + c * 64 + lane] = (pos < CAP) ? e * CAP + pos : -1;
        }
        cnt += __popcll(m);
    }

    // ---- rank 1 (prev = min(cnt, CAP)) ----
    int e1v[32];
    #pragma unroll
    for (int c = 0; c < 32; ++c) e1v[c] = e1enc[base_tok + c * 64 + lane];

    int cnt1 = min(cnt, CAP);
    #pragma unroll
    for (int c = 0; c < 32; ++c) {
        bool sel = ((e1v[c] & 7) == e);           // this wave owns the write
        bool hit = sel && (e1v[c] & 8);           // actually routed
        unsigned long long m = __ballot(hit);
        if (sel) {
            int pos = cnt1 + __popcll(m & lt);
            t1[base_tok + c * 64 + lane] = (hit && pos < CAP) ? e * CAP + pos : -1;
        }
        cnt1 += __popcll(m);
    }
}

// ---------------- Kernel 3: single-stream fill + merged scatter --------------
// grid = 8192 blocks x 256 threads. The store stream is IDENTICAL to
// fillBufferAligned: block i writes the contiguous 32KB chunk at i*32KB of
// the flat [dispatch|combine] output. Blocks 0-4095 cover dispatch (2 token-
// rows each), 4096-8191 cover combine. Targets are 4 block-uniform scalar
// loads; row select per store is compile-time (k>>2). Rare uniform-false
// branch inserts the <=2 nonzero windows. Plain stores (no NT).
__global__ __launch_bounds__(256) void fill_scatter_kernel(
    const int* __restrict__ t0, const int* __restrict__ t1,
    const float* __restrict__ v0, const float* __restrict__ v1,
    f32x4* __restrict__ out)
{
    const int blk = blockIdx.x;
    const int tid = threadIdx.x;
    const bool comb = blk >= 4096;
    const int tokbase = (blk & 4095) * 2;     // two token-rows per block

    int a0r0 = t0[tokbase + 0], a1r0 = t1[tokbase + 0];
    int a0r1 = t0[tokbase + 1], a1r1 = t1[tokbase + 1];
    float x0r0 = 1.f, x1r0 = 1.f, x0r1 = 1.f, x1r1 = 1.f;
    if (comb) {
        x0r0 = v0[tokbase + 0]; x1r0 = v1[tokbase + 0];
        x0r1 = v0[tokbase + 1]; x1r1 = v1[tokbase + 1];
    }
    const int w0r0 = a0r0 >> 2, w1r0 = a1r0 >> 2;   // -1 never matches
    const int w0r1 = a0r1 >> 2, w1r1 = a1r1 >> 2;

    f32x4* chunk = out + (size_t)blk * 2048;

    #pragma unroll
    for (int k = 0; k < 8; ++k) {
        const int widx = k * 256 + tid;       // 0..2047 within chunk
        const int win  = widx & 1023;         // window within token-row
        // compile-time row select (k>>2): no dynamic array indexing
        const int a0 = (k < 4) ? a0r0 : a0r1;
        const int a1 = (k < 4) ? a1r0 : a1r1;
        const int w0 = (k < 4) ? w0r0 : w0r1;
        const int w1 = (k < 4) ? w1r0 : w1r1;
        const float x0 = (k < 4) ? x0r0 : x0r1;
        const float x1 = (k < 4) ? x1r0 : x1r1;

        f32x4 val = (f32x4)(0.f);
        if (win == w0 || win == w1) {         // <=2 lanes per block total
            const int f = win * 4;
            val.x = (f + 0 == a0) ? x0 : ((f + 0 == a1) ? x1 : 0.f);
            val.y = (f + 1 == a0) ? x0 : ((f + 1 == a1) ? x1 : 0.f);
            val.z = (f + 2 == a0) ? x0 : ((f + 2 == a1) ? x1 : 0.f);
            val.w = (f + 3 == a0) ? x0 : ((f + 3 == a1) ? x1 : 0.f);
        }
        chunk[widx] = val;
    }
}

extern "C" void kernel_launch(void* const* d_in, const int* in_sizes, int n_in,
                              void* d_out, int out_size, void* d_ws, size_t ws_size,
                              hipStream_t stream) {
    const float* x     = (const float*)d_in[0];
    const float* w     = (const float*)d_in[1];
    const float* probs = (const float*)d_in[2];
    float* out = (float*)d_out;

    int*   e0 = (int*)d_ws;
    int*   e1 = e0 + NTOK;
    int*   t0 = e1 + NTOK;
    int*   t1 = t0 + NTOK;
    float* v0 = (float*)(t1 + NTOK);
    float* v1 = v0 + NTOK;

    gate_kernel<<<2048, 256, 0, stream>>>(x, w, probs, e0, e1, v0, v1);
    scan_kernel<<<32, 64, 0, stream>>>(e0, e1, t0, t1);
    fill_scatter_kernel<<<8192, 256, 0, stream>>>(t0, t1, v0, v1, (f32x4*)out);
}